// Round 2
// baseline (11125.982 us; speedup 1.0000x reference)
//
#include <hip/hip_runtime.h>
#include <hip/hip_bf16.h>

typedef __attribute__((ext_vector_type(8))) short short8;
typedef __attribute__((ext_vector_type(4))) float floatx4;

#define N_SAMP 64
#define HIDN   1024
#define EMBN   1024
#define SEQ    512
#define KTOT   2048
#define NBLK   256
#define NTHR   256

__device__ __forceinline__ float sigm(float x){ return __builtin_amdgcn_rcpf(1.f + __expf(-x)); }
__device__ __forceinline__ float tanh_fast(float x){ return 2.f*__builtin_amdgcn_rcpf(1.f + __expf(-2.f*x)) - 1.f; }
__device__ __forceinline__ unsigned short f2bf(float f){
  unsigned u = __float_as_uint(f);
  return (unsigned short)((u + 0x7FFFu + ((u >> 16) & 1u)) >> 16);
}
// load 8 consecutive fp32, round-to-nearest-even to bf16, pack as MFMA A-frag chunk
__device__ __forceinline__ short8 ld8_f32_bf16(const float* p){
  floatx4 a = *reinterpret_cast<const floatx4*>(p);
  floatx4 b = *reinterpret_cast<const floatx4*>(p + 4);
  short8 r;
  r[0]=(short)f2bf(a[0]); r[1]=(short)f2bf(a[1]); r[2]=(short)f2bf(a[2]); r[3]=(short)f2bf(a[3]);
  r[4]=(short)f2bf(b[0]); r[5]=(short)f2bf(b[1]); r[6]=(short)f2bf(b[2]); r[7]=(short)f2bf(b[3]);
  return r;
}

// 256 blocks x 256 threads, cooperative. Block b owns hidden units [4b,4b+4)
// -> 16 gate columns {g*1024 + 4b + j}. W slice (fp32 -> bf16) lives in LDS in
// MFMA B-fragment layout for all 512 steps. H double buffer (bf16, internal)
// + barrier counter live in ws. Inputs fp32, output fp32.
__launch_bounds__(NTHR, 1)
__global__ void lstm_kernel(const int* __restrict__ Xi, const float* __restrict__ E,
                            const float* __restrict__ Ww, const float* __restrict__ Wb,
                            float* __restrict__ Out, unsigned short* __restrict__ Hbuf,
                            unsigned* __restrict__ Cnt)
{
  __shared__ short8 Wlds[64][64];   // [k-block][lane] B-fragment, 64 KB
  const int tid  = threadIdx.x;
  const int lane = tid & 63;
  const int wave = tid >> 6;        // 0..3, wave w covers samples [16w,16w+16)
  const int u0   = blockIdx.x * 4;

  // ---- stage W slice into LDS as pre-swizzled bf16 B-fragments (once) ----
  // B[k][n] = Wt[k][gcol(n)] = W_w[gcol][k]; frag(lane l, j) = B[kb*32 + (l>>4)*8 + j][l&15]
  for (int e = tid; e < 4096; e += NTHR){
    int kb = e >> 6, l = e & 63;
    int n = l & 15, kq2 = l >> 4;
    int gcol = ((n >> 2) << 10) + u0 + (n & 3);
    int k = kb*32 + kq2*8;
    Wlds[kb][l] = ld8_f32_bf16(Ww + (size_t)gcol*KTOT + k);
  }

  const int kq   = lane >> 4;
  const int m    = wave*16 + (lane & 15);   // sample row for A-operand role
  const int ul   = lane & 3;                // unit within block (epilogue role)
  const int gate = (lane >> 2) & 3;

  // biases for unit u0+ul (only gate==0 lanes consume)
  const float bi = Wb[0*HIDN + u0 + ul];
  const float bf = Wb[1*HIDN + u0 + ul];
  const float bo = Wb[2*HIDN + u0 + ul];
  const float bg = Wb[3*HIDN + u0 + ul];

  float C[4] = {0.f, 0.f, 0.f, 0.f};

  __syncthreads();

  unsigned short* hb0 = Hbuf;
  unsigned short* hb1 = Hbuf + N_SAMP*HIDN;

  // ---- prefetch x-part for t=0 (no H dependency) ----
  floatx4 accE = {0.f, 0.f, 0.f, 0.f};
  {
    int tok = Xi[m*SEQ + 0];
    const float* xr = E + (size_t)tok*EMBN + kq*8;
    #pragma unroll
    for (int kb = 0; kb < 32; ++kb)
      accE = __builtin_amdgcn_mfma_f32_16x16x32_bf16(ld8_f32_bf16(xr + kb*32), Wlds[32+kb][lane], accE, 0, 0, 0);
  }

  for (int t = 0; t < SEQ; ++t){
    const unsigned short* hprev = (t & 1) ? hb1 : hb0;   // t=0 reads zeroed hb0
    unsigned short*       hnext = (t & 1) ? hb0 : hb1;

    // ---- recurrent H-part: acc += H_{t-1} @ Wh_slice ----
    floatx4 acc = accE;
    const short8* hp = reinterpret_cast<const short8*>(hprev + m*HIDN + kq*8);
    #pragma unroll
    for (int kb = 0; kb < 32; ++kb)
      acc = __builtin_amdgcn_mfma_f32_16x16x32_bf16(hp[kb*4], Wlds[kb][lane], acc, 0, 0, 0);

    // ---- gather i,f,o,g across lanes (D: col=lane&15, row=(lane>>4)*4+reg) ----
    // holder of pre[sample kq*4+r][g*4+ul] is lane kq*16 + g*4 + ul, reg r
    int base = lane & 51;             // kq*16 + ul
    float v0[4], v1[4], v2[4], v3[4];
    #pragma unroll
    for (int r = 0; r < 4; ++r){
      v0[r] = __shfl(acc[r], base);
      v1[r] = __shfl(acc[r], base | 4);
      v2[r] = __shfl(acc[r], base | 8);
      v3[r] = __shfl(acc[r], base | 12);
    }
    if (gate == 0){
      #pragma unroll
      for (int r = 0; r < 4; ++r){
        float iv = sigm(v0[r] + bi);
        float fv = sigm(v1[r] + bf);
        float ov = sigm(v2[r] + bo);
        float gv = tanh_fast(v3[r] + bg);
        C[r] = fv*C[r] + iv*gv;
        float hv = ov*tanh_fast(C[r]);
        int s = wave*16 + kq*4 + r;
        hnext[s*HIDN + u0 + ul] = f2bf(hv);
        if (t == SEQ-1) Out[s*HIDN + u0 + ul] = hv;   // fp32 output
      }
    }

    // ---- grid barrier with x-part(t+1) hidden under the wait ----
    if (t < SEQ-1){
      __syncthreads();                       // all waves' H stores drained
      if (tid == 0){
        __threadfence();                     // release: make H_t agent-visible
        atomicAdd(Cnt, 1u);
      }
      floatx4 aE = {0.f, 0.f, 0.f, 0.f};
      int tok = Xi[m*SEQ + t + 1];
      const float* xr = E + (size_t)tok*EMBN + kq*8;
      #pragma unroll
      for (int kb = 0; kb < 32; ++kb)
        aE = __builtin_amdgcn_mfma_f32_16x16x32_bf16(ld8_f32_bf16(xr + kb*32), Wlds[32+kb][lane], aE, 0, 0, 0);
      accE = aE;
      if (tid == 0){
        unsigned tgt = (unsigned)NBLK * (unsigned)(t + 1);
        while (__hip_atomic_load(Cnt, __ATOMIC_RELAXED, __HIP_MEMORY_SCOPE_AGENT) < tgt)
          __builtin_amdgcn_s_sleep(2);
        __threadfence();                     // acquire: discard stale cached H
      }
      __syncthreads();
    }
  }
}

extern "C" void kernel_launch(void* const* d_in, const int* in_sizes, int n_in,
                              void* d_out, int out_size, void* d_ws, size_t ws_size,
                              hipStream_t stream) {
  const int*   Xi = (const int*)d_in[0];
  const float* E  = (const float*)d_in[1];
  const float* Ww = (const float*)d_in[2];
  const float* Wb = (const float*)d_in[3];
  float*       out = (float*)d_out;
  unsigned short* hbuf = (unsigned short*)d_ws;                  // 2 x 128 KB bf16 H double buffer
  unsigned*       cnt  = (unsigned*)((char*)d_ws + 262144);      // barrier counter

  // zero H_0 buffer + barrier counter (graph-capturable)
  hipMemsetAsync(d_ws, 0, 262144 + 256, stream);

  void* args[] = {(void*)&Xi, (void*)&E, (void*)&Ww, (void*)&Wb,
                  (void*)&out, (void*)&hbuf, (void*)&cnt};
  hipLaunchCooperativeKernel((void*)lstm_kernel, dim3(NBLK), dim3(NTHR), args, 0, stream);
}

// Round 3
// 9604.266 us; speedup vs baseline: 1.1584x; 1.1584x over previous
//
#include <hip/hip_runtime.h>
#include <hip/hip_bf16.h>

typedef __attribute__((ext_vector_type(8))) short short8;
typedef __attribute__((ext_vector_type(4))) float floatx4;

#define N_SAMP 64
#define HIDN   1024
#define EMBN   1024
#define SEQ    512
#define KTOT   2048
#define NBLK   256
#define NTHR   256

// ws layout (main path)
#define WS_HBUF   0u
#define WS_SYNC   262144u            // flags[256] at +0, Rel at +2048
#define WS_XE     270336u            // 32768 x 1024 bf16 = 67,108,864
#define WS_WXB    67379200u          // 4096 x 1024 bf16  =  8,388,608
#define WS_G      75767808u          // 32768 x 4096 bf16 = 268,435,456
#define WS_NEED   344203264ull

__device__ __forceinline__ float sigm(float x){ return __builtin_amdgcn_rcpf(1.f + __expf(-x)); }
__device__ __forceinline__ float tanh_fast(float x){ return 2.f*__builtin_amdgcn_rcpf(1.f + __expf(-2.f*x)) - 1.f; }
__device__ __forceinline__ unsigned short f2bf(float f){
  unsigned u = __float_as_uint(f);
  return (unsigned short)((u + 0x7FFFu + ((u >> 16) & 1u)) >> 16);
}
__device__ __forceinline__ float bf2f(unsigned v){ return __uint_as_float((v & 0xffffu) << 16); }
__device__ __forceinline__ short8 ld8_f32_bf16(const float* p){
  floatx4 a = *reinterpret_cast<const floatx4*>(p);
  floatx4 b = *reinterpret_cast<const floatx4*>(p + 4);
  short8 r;
  r[0]=(short)f2bf(a[0]); r[1]=(short)f2bf(a[1]); r[2]=(short)f2bf(a[2]); r[3]=(short)f2bf(a[3]);
  r[4]=(short)f2bf(b[0]); r[5]=(short)f2bf(b[1]); r[6]=(short)f2bf(b[2]); r[7]=(short)f2bf(b[3]);
  return r;
}

// ---------------- gather/convert: Xe = bf16(E[X]), Wxb = bf16(Wx) ----------------
__global__ void gather_cvt(const int* __restrict__ Xi, const float* __restrict__ E,
                           const float* __restrict__ Ww,
                           unsigned short* __restrict__ Xe, unsigned short* __restrict__ Wxb)
{
  const int tid = threadIdx.x;
  const int inner = (tid & 127) * 8;
  if (blockIdx.x < 16384){
    int row = blockIdx.x*2 + (tid >> 7);
    int tok = Xi[row];
    short8 v = ld8_f32_bf16(E + (size_t)tok*EMBN + inner);
    *reinterpret_cast<short8*>(Xe + (size_t)row*EMBN + inner) = v;
  } else {
    int n = (blockIdx.x - 16384)*2 + (tid >> 7);
    short8 v = ld8_f32_bf16(Ww + (size_t)n*KTOT + HIDN + inner);
    *reinterpret_cast<short8*>(Wxb + (size_t)n*EMBN + inner) = v;
  }
}

// ---------------- precompute GEMM: G = Xe @ Wxb^T + bias, packed layout ----------------
// grid 4096 = 128 row-blocks (BM=256) x 32 col-blocks (BN=128); K=1024, BK=32
__launch_bounds__(256, 2)
__global__ void gemm_x(const unsigned short* __restrict__ Xe, const unsigned short* __restrict__ Wxb,
                       const float* __restrict__ Wb, unsigned short* __restrict__ G)
{
  __shared__ unsigned short As[256][40];   // +8 pad, 16B-aligned rows
  __shared__ unsigned short Bs[128][40];
  const int tid  = threadIdx.x;
  const int lane = tid & 63, wave = tid >> 6;
  const int rb = blockIdx.x >> 5, cb = blockIdx.x & 31;
  const int r0 = rb * 256, c0 = cb * 128;
  const int mloc = lane & 15, kq = lane >> 4;

  floatx4 acc[4][8];
  #pragma unroll
  for (int i=0;i<4;++i)
    #pragma unroll
    for (int j=0;j<8;++j) acc[i][j] = (floatx4){0.f,0.f,0.f,0.f};

  for (int kb = 0; kb < 32; ++kb){
    int k0 = kb * 32;
    __syncthreads();
    #pragma unroll
    for (int idx = tid; idx < 1024; idx += 256){
      int row = idx >> 2, ch = idx & 3;
      *reinterpret_cast<uint4*>(&As[row][ch*8]) =
        *reinterpret_cast<const uint4*>(&Xe[(size_t)(r0+row)*1024 + k0 + ch*8]);
    }
    #pragma unroll
    for (int idx = tid; idx < 512; idx += 256){
      int n = idx >> 2, ch = idx & 3;
      *reinterpret_cast<uint4*>(&Bs[n][ch*8]) =
        *reinterpret_cast<const uint4*>(&Wxb[(size_t)(c0+n)*1024 + k0 + ch*8]);
    }
    __syncthreads();
    short8 af[4], bfr[8];
    #pragma unroll
    for (int rt=0; rt<4; ++rt) af[rt]  = *reinterpret_cast<const short8*>(&As[wave*64 + rt*16 + mloc][kq*8]);
    #pragma unroll
    for (int ct=0; ct<8; ++ct) bfr[ct] = *reinterpret_cast<const short8*>(&Bs[ct*16 + mloc][kq*8]);
    #pragma unroll
    for (int rt=0; rt<4; ++rt)
      #pragma unroll
      for (int ct=0; ct<8; ++ct)
        acc[rt][ct] = __builtin_amdgcn_mfma_f32_16x16x32_bf16(af[rt], bfr[ct], acc[rt][ct], 0,0,0);
  }

  // epilogue: add bias, pack into consumption layout
  // G addr = ((((t*256 + b)*4 + w)*16 + (kqc*4 + ul))*16 + (g*4 + rc)
  const int s  = r0 >> 9;                     // uniform per block
  const int wc = s >> 4, kqc = (s >> 2) & 3, rc = s & 3;
  #pragma unroll
  for (int rt=0; rt<4; ++rt){
    int rowbase = r0 + wave*64 + rt*16 + kq*4;
    #pragma unroll
    for (int ct=0; ct<8; ++ct){
      int col = c0 + ct*16 + mloc;
      float bias = Wb[col];
      int g = col >> 10, bb = (col >> 2) & 255, ul = col & 3;
      #pragma unroll
      for (int r=0; r<4; ++r){
        int t = (rowbase + r) & 511;
        size_t addr = ((((size_t)t*256 + bb)*4 + wc)*16 + (kqc*4 + ul))*16 + (g*4 + rc);
        G[addr] = f2bf(acc[rt][ct][r] + bias);
      }
    }
  }
}

// ---------------- recurrence: 256 blocks cooperative ----------------
__launch_bounds__(NTHR, 1)
__global__ void lstm_main(const float* __restrict__ Ww, const unsigned short* __restrict__ G,
                          float* __restrict__ Out, unsigned short* __restrict__ Hbuf,
                          unsigned* __restrict__ Sync)
{
  __shared__ short8 Wlds[32][64];   // H-part W slice, B-frag layout, 32 KB
  const int tid  = threadIdx.x;
  const int lane = tid & 63;
  const int wave = tid >> 6;
  const int b    = blockIdx.x;
  const int u0   = b * 4;

  unsigned* flags = Sync;                 // [256]
  unsigned* Rel   = Sync + 512;           // separate line

  // stage H-part W (k in [0,1024)) as bf16 B-fragments
  for (int e = tid; e < 2048; e += NTHR){
    int kb = e >> 6, l = e & 63;
    int n = l & 15, kq2 = l >> 4;
    int gcol = ((n >> 2) << 10) + u0 + (n & 3);
    int k = kb*32 + kq2*8;
    Wlds[kb][l] = ld8_f32_bf16(Ww + (size_t)gcol*KTOT + k);
  }

  const int kq   = lane >> 4;
  const int m    = wave*16 + (lane & 15);
  const int ul   = lane & 3;
  const int gate = (lane >> 2) & 3;

  float C[4] = {0.f, 0.f, 0.f, 0.f};

  unsigned short* hb0 = Hbuf;
  unsigned short* hb1 = Hbuf + N_SAMP*HIDN;

  __syncthreads();

  // prefetch gx(0): 16 bf16 per lane, contiguous 32B
  const unsigned short* gbase = G + (((size_t)b*4 + wave)*16 + (kq*4 + ul))*16;
  uint4 gxa = *reinterpret_cast<const uint4*>(gbase);
  uint4 gxb = *reinterpret_cast<const uint4*>(gbase + 8);

  for (int t = 0; t < SEQ; ++t){
    const unsigned short* hprev = (t & 1) ? hb1 : hb0;
    unsigned short*       hnext = (t & 1) ? hb0 : hb1;

    // H-part MFMA
    floatx4 acc = {0.f, 0.f, 0.f, 0.f};
    const short8* hp = reinterpret_cast<const short8*>(hprev + m*HIDN + kq*8);
    #pragma unroll
    for (int kb = 0; kb < 32; ++kb)
      acc = __builtin_amdgcn_mfma_f32_16x16x32_bf16(hp[kb*4], Wlds[kb][lane], acc, 0, 0, 0);

    // gather i,f,o,g across lanes
    int base = lane & 51;
    float v0[4], v1[4], v2[4], v3[4];
    #pragma unroll
    for (int r = 0; r < 4; ++r){
      v0[r] = __shfl(acc[r], base);
      v1[r] = __shfl(acc[r], base | 4);
      v2[r] = __shfl(acc[r], base | 8);
      v3[r] = __shfl(acc[r], base | 12);
    }
    if (gate == 0){
      unsigned gw[8] = {gxa.x,gxa.y,gxa.z,gxa.w,gxb.x,gxb.y,gxb.z,gxb.w};
      #pragma unroll
      for (int r = 0; r < 4; ++r){
        float iv = sigm(v0[r] + bf2f(gw[(0+ (r>>1))] >> ((r&1)*16)));
        float fv = sigm(v1[r] + bf2f(gw[(2+ (r>>1))] >> ((r&1)*16)));
        float ov = sigm(v2[r] + bf2f(gw[(4+ (r>>1))] >> ((r&1)*16)));
        float gv = tanh_fast(v3[r] + bf2f(gw[(6+ (r>>1))] >> ((r&1)*16)));
        C[r] = fv*C[r] + iv*gv;
        float hv = ov*tanh_fast(C[r]);
        int s = wave*16 + kq*4 + r;
        hnext[s*HIDN + u0 + ul] = f2bf(hv);
        if (t == SEQ-1) Out[s*HIDN + u0 + ul] = hv;
      }
    }

    if (t < SEQ-1){
      // prefetch gx(t+1) into registers (read-only; survives cache inv)
      const unsigned short* gp = gbase + ((size_t)(t+1)*256)*1024;
      gxa = *reinterpret_cast<const uint4*>(gp);
      gxb = *reinterpret_cast<const uint4*>(gp + 8);

      __syncthreads();                     // all H stores drained
      if (wave == 0){
        __threadfence();                   // release
        if (lane == 0)
          __hip_atomic_store(&flags[b], (unsigned)(t+1), __ATOMIC_RELAXED, __HIP_MEMORY_SCOPE_AGENT);
        if (b == 0){
          for (;;){
            bool ok = true;
            #pragma unroll
            for (int j = 0; j < 4; ++j){
              unsigned f = __hip_atomic_load(&flags[lane*4 + j], __ATOMIC_RELAXED, __HIP_MEMORY_SCOPE_AGENT);
              ok &= (f >= (unsigned)(t+1));
            }
            if (__all(ok)) break;
            __builtin_amdgcn_s_sleep(1);
          }
          if (lane == 0)
            __hip_atomic_store(Rel, (unsigned)(t+1), __ATOMIC_RELAXED, __HIP_MEMORY_SCOPE_AGENT);
        } else if (lane == 0){
          while (__hip_atomic_load(Rel, __ATOMIC_RELAXED, __HIP_MEMORY_SCOPE_AGENT) < (unsigned)(t+1))
            __builtin_amdgcn_s_sleep(2);
        }
        __threadfence();                   // acquire
      }
      __syncthreads();
    }
  }
}

// ---------------- fallback (round-2 kernel, used if ws too small) ----------------
__launch_bounds__(NTHR, 1)
__global__ void lstm_fb(const int* __restrict__ Xi, const float* __restrict__ E,
                        const float* __restrict__ Ww, const float* __restrict__ Wb,
                        float* __restrict__ Out, unsigned short* __restrict__ Hbuf,
                        unsigned* __restrict__ Cnt)
{
  __shared__ short8 Wlds[64][64];
  const int tid  = threadIdx.x;
  const int lane = tid & 63;
  const int wave = tid >> 6;
  const int u0   = blockIdx.x * 4;
  for (int e = tid; e < 4096; e += NTHR){
    int kb = e >> 6, l = e & 63;
    int n = l & 15, kq2 = l >> 4;
    int gcol = ((n >> 2) << 10) + u0 + (n & 3);
    int k = kb*32 + kq2*8;
    Wlds[kb][l] = ld8_f32_bf16(Ww + (size_t)gcol*KTOT + k);
  }
  const int kq   = lane >> 4;
  const int m    = wave*16 + (lane & 15);
  const int ul   = lane & 3;
  const int gate = (lane >> 2) & 3;
  const float bi = Wb[0*HIDN + u0 + ul];
  const float bf = Wb[1*HIDN + u0 + ul];
  const float bo = Wb[2*HIDN + u0 + ul];
  const float bg = Wb[3*HIDN + u0 + ul];
  float C[4] = {0.f, 0.f, 0.f, 0.f};
  __syncthreads();
  unsigned short* hb0 = Hbuf;
  unsigned short* hb1 = Hbuf + N_SAMP*HIDN;
  floatx4 accE = {0.f, 0.f, 0.f, 0.f};
  {
    int tok = Xi[m*SEQ + 0];
    const float* xr = E + (size_t)tok*EMBN + kq*8;
    #pragma unroll
    for (int kb = 0; kb < 32; ++kb)
      accE = __builtin_amdgcn_mfma_f32_16x16x32_bf16(ld8_f32_bf16(xr + kb*32), Wlds[32+kb][lane], accE, 0, 0, 0);
  }
  for (int t = 0; t < SEQ; ++t){
    const unsigned short* hprev = (t & 1) ? hb1 : hb0;
    unsigned short*       hnext = (t & 1) ? hb0 : hb1;
    floatx4 acc = accE;
    const short8* hp = reinterpret_cast<const short8*>(hprev + m*HIDN + kq*8);
    #pragma unroll
    for (int kb = 0; kb < 32; ++kb)
      acc = __builtin_amdgcn_mfma_f32_16x16x32_bf16(hp[kb*4], Wlds[kb][lane], acc, 0, 0, 0);
    int base = lane & 51;
    float v0[4], v1[4], v2[4], v3[4];
    #pragma unroll
    for (int r = 0; r < 4; ++r){
      v0[r] = __shfl(acc[r], base);
      v1[r] = __shfl(acc[r], base | 4);
      v2[r] = __shfl(acc[r], base | 8);
      v3[r] = __shfl(acc[r], base | 12);
    }
    if (gate == 0){
      #pragma unroll
      for (int r = 0; r < 4; ++r){
        float iv = sigm(v0[r] + bi);
        float fv = sigm(v1[r] + bf);
        float ov = sigm(v2[r] + bo);
        float gv = tanh_fast(v3[r] + bg);
        C[r] = fv*C[r] + iv*gv;
        float hv = ov*tanh_fast(C[r]);
        int s = wave*16 + kq*4 + r;
        hnext[s*HIDN + u0 + ul] = f2bf(hv);
        if (t == SEQ-1) Out[s*HIDN + u0 + ul] = hv;
      }
    }
    if (t < SEQ-1){
      __syncthreads();
      if (tid == 0){ __threadfence(); atomicAdd(Cnt, 1u); }
      floatx4 aE = {0.f, 0.f, 0.f, 0.f};
      int tok = Xi[m*SEQ + t + 1];
      const float* xr = E + (size_t)tok*EMBN + kq*8;
      #pragma unroll
      for (int kb = 0; kb < 32; ++kb)
        aE = __builtin_amdgcn_mfma_f32_16x16x32_bf16(ld8_f32_bf16(xr + kb*32), Wlds[32+kb][lane], aE, 0, 0, 0);
      accE = aE;
      if (tid == 0){
        unsigned tgt = (unsigned)NBLK * (unsigned)(t + 1);
        while (__hip_atomic_load(Cnt, __ATOMIC_RELAXED, __HIP_MEMORY_SCOPE_AGENT) < tgt)
          __builtin_amdgcn_s_sleep(2);
        __threadfence();
      }
      __syncthreads();
    }
  }
}

extern "C" void kernel_launch(void* const* d_in, const int* in_sizes, int n_in,
                              void* d_out, int out_size, void* d_ws, size_t ws_size,
                              hipStream_t stream) {
  const int*   Xi = (const int*)d_in[0];
  const float* E  = (const float*)d_in[1];
  const float* Ww = (const float*)d_in[2];
  const float* Wb = (const float*)d_in[3];
  float*       out = (float*)d_out;

  if (ws_size >= WS_NEED){
    unsigned short* hbuf = (unsigned short*)((char*)d_ws + WS_HBUF);
    unsigned*       sync = (unsigned*)((char*)d_ws + WS_SYNC);
    unsigned short* xe   = (unsigned short*)((char*)d_ws + WS_XE);
    unsigned short* wxb  = (unsigned short*)((char*)d_ws + WS_WXB);
    unsigned short* g    = (unsigned short*)((char*)d_ws + WS_G);

    hipMemsetAsync(d_ws, 0, WS_XE, stream);   // zero Hbuf + sync flags

    gather_cvt<<<18432, 256, 0, stream>>>(Xi, E, Ww, xe, wxb);
    gemm_x<<<4096, 256, 0, stream>>>(xe, wxb, Wb, g);

    void* args[] = {(void*)&Ww, (void*)&g, (void*)&out, (void*)&hbuf, (void*)&sync};
    hipLaunchCooperativeKernel((void*)lstm_main, dim3(NBLK), dim3(NTHR), args, 0, stream);
  } else {
    unsigned short* hbuf = (unsigned short*)d_ws;
    unsigned*       cnt  = (unsigned*)((char*)d_ws + 262144);
    hipMemsetAsync(d_ws, 0, 262144 + 256, stream);
    void* args[] = {(void*)&Xi, (void*)&E, (void*)&Ww, (void*)&Wb,
                    (void*)&out, (void*)&hbuf, (void*)&cnt};
    hipLaunchCooperativeKernel((void*)lstm_fb, dim3(NBLK), dim3(NTHR), args, 0, stream);
  }
}

// Round 5
// 7167.055 us; speedup vs baseline: 1.5524x; 1.3401x over previous
//
#include <hip/hip_runtime.h>
#include <hip/hip_bf16.h>

typedef __attribute__((ext_vector_type(8))) short short8;
typedef __attribute__((ext_vector_type(4))) float floatx4;

#define N_SAMP 64
#define HIDN   1024
#define EMBN   1024
#define SEQ    512
#define KTOT   2048
#define NBLK   256
#define NTHR   256

// ws layout (main path)
#define WS_HBUF   0u
#define WS_SYNC   262144u            // flags[256]
#define WS_XE     270336u            // 32768 x 1024 bf16 = 67,108,864
#define WS_WXB    67379200u          // 4096 x 1024 bf16  =  8,388,608
#define WS_G      75767808u          // 32768 x 4096 bf16 = 268,435,456
#define WS_NEED   344203264ull

__device__ __forceinline__ float sigm(float x){ return __builtin_amdgcn_rcpf(1.f + __expf(-x)); }
__device__ __forceinline__ float tanh_fast(float x){ return 2.f*__builtin_amdgcn_rcpf(1.f + __expf(-2.f*x)) - 1.f; }
__device__ __forceinline__ unsigned short f2bf(float f){
  unsigned u = __float_as_uint(f);
  return (unsigned short)((u + 0x7FFFu + ((u >> 16) & 1u)) >> 16);
}
__device__ __forceinline__ float bf2f(unsigned v){ return __uint_as_float((v & 0xffffu) << 16); }
__device__ __forceinline__ short8 ld8_f32_bf16(const float* p){
  floatx4 a = *reinterpret_cast<const floatx4*>(p);
  floatx4 b = *reinterpret_cast<const floatx4*>(p + 4);
  short8 r;
  r[0]=(short)f2bf(a[0]); r[1]=(short)f2bf(a[1]); r[2]=(short)f2bf(a[2]); r[3]=(short)f2bf(a[3]);
  r[4]=(short)f2bf(b[0]); r[5]=(short)f2bf(b[1]); r[6]=(short)f2bf(b[2]); r[7]=(short)f2bf(b[3]);
  return r;
}

struct LL2 { unsigned long long a, b; };

// relaxed agent-scope accessors -> compiler emits coherence-point (sc1) ops, no fences
__device__ __forceinline__ unsigned long long ld_agent_u64(const void* p){
  return __hip_atomic_load((const unsigned long long*)p, __ATOMIC_RELAXED, __HIP_MEMORY_SCOPE_AGENT);
}
__device__ __forceinline__ void st_agent_u32(unsigned* p, unsigned v){
  __hip_atomic_store(p, v, __ATOMIC_RELAXED, __HIP_MEMORY_SCOPE_AGENT);
}

// ---------------- gather/convert: Xe = bf16(E[X]), Wxb = bf16(Wx) ----------------
__global__ void gather_cvt(const int* __restrict__ Xi, const float* __restrict__ E,
                           const float* __restrict__ Ww,
                           unsigned short* __restrict__ Xe, unsigned short* __restrict__ Wxb)
{
  const int tid = threadIdx.x;
  const int inner = (tid & 127) * 8;
  if (blockIdx.x < 16384){
    int row = blockIdx.x*2 + (tid >> 7);
    int tok = Xi[row];
    short8 v = ld8_f32_bf16(E + (size_t)tok*EMBN + inner);
    *reinterpret_cast<short8*>(Xe + (size_t)row*EMBN + inner) = v;
  } else {
    int n = (blockIdx.x - 16384)*2 + (tid >> 7);
    short8 v = ld8_f32_bf16(Ww + (size_t)n*KTOT + HIDN + inner);
    *reinterpret_cast<short8*>(Wxb + (size_t)n*EMBN + inner) = v;
  }
}

// ---------------- precompute GEMM: G = Xe @ Wxb^T + bias, packed layout ----------------
__launch_bounds__(256, 2)
__global__ void gemm_x(const unsigned short* __restrict__ Xe, const unsigned short* __restrict__ Wxb,
                       const float* __restrict__ Wb, unsigned short* __restrict__ G)
{
  __shared__ unsigned short As[256][40];
  __shared__ unsigned short Bs[128][40];
  const int tid  = threadIdx.x;
  const int lane = tid & 63, wave = tid >> 6;
  const int rb = blockIdx.x >> 5, cb = blockIdx.x & 31;
  const int r0 = rb * 256, c0 = cb * 128;
  const int mloc = lane & 15, kq = lane >> 4;

  floatx4 acc[4][8];
  #pragma unroll
  for (int i=0;i<4;++i)
    #pragma unroll
    for (int j=0;j<8;++j) acc[i][j] = (floatx4){0.f,0.f,0.f,0.f};

  for (int kb = 0; kb < 32; ++kb){
    int k0 = kb * 32;
    __syncthreads();
    #pragma unroll
    for (int idx = tid; idx < 1024; idx += 256){
      int row = idx >> 2, ch = idx & 3;
      *reinterpret_cast<uint4*>(&As[row][ch*8]) =
        *reinterpret_cast<const uint4*>(&Xe[(size_t)(r0+row)*1024 + k0 + ch*8]);
    }
    #pragma unroll
    for (int idx = tid; idx < 512; idx += 256){
      int n = idx >> 2, ch = idx & 3;
      *reinterpret_cast<uint4*>(&Bs[n][ch*8]) =
        *reinterpret_cast<const uint4*>(&Wxb[(size_t)(c0+n)*1024 + k0 + ch*8]);
    }
    __syncthreads();
    short8 af[4], bfr[8];
    #pragma unroll
    for (int rt=0; rt<4; ++rt) af[rt]  = *reinterpret_cast<const short8*>(&As[wave*64 + rt*16 + mloc][kq*8]);
    #pragma unroll
    for (int ct=0; ct<8; ++ct) bfr[ct] = *reinterpret_cast<const short8*>(&Bs[ct*16 + mloc][kq*8]);
    #pragma unroll
    for (int rt=0; rt<4; ++rt)
      #pragma unroll
      for (int ct=0; ct<8; ++ct)
        acc[rt][ct] = __builtin_amdgcn_mfma_f32_16x16x32_bf16(af[rt], bfr[ct], acc[rt][ct], 0,0,0);
  }

  const int s  = r0 >> 9;
  const int wc = s >> 4, kqc = (s >> 2) & 3, rc = s & 3;
  #pragma unroll
  for (int rt=0; rt<4; ++rt){
    int rowbase = r0 + wave*64 + rt*16 + kq*4;
    #pragma unroll
    for (int ct=0; ct<8; ++ct){
      int col = c0 + ct*16 + mloc;
      float bias = Wb[col];
      int g = col >> 10, bb = (col >> 2) & 255, ul = col & 3;
      #pragma unroll
      for (int r=0; r<4; ++r){
        int t = (rowbase + r) & 511;
        size_t addr = ((((size_t)t*256 + bb)*4 + wc)*16 + (kqc*4 + ul))*16 + (g*4 + rc);
        G[addr] = f2bf(acc[rt][ct][r] + bias);
      }
    }
  }
}

// ---------------- recurrence: 256 blocks cooperative, fence-free via agent atomics ----------------
__launch_bounds__(NTHR, 1)
__global__ void lstm_main(const float* __restrict__ Ww, const unsigned short* __restrict__ G,
                          float* __restrict__ Out, unsigned short* __restrict__ Hbuf,
                          unsigned* __restrict__ Sync)
{
  __shared__ short8 Wlds[32][64];
  const int tid  = threadIdx.x;
  const int lane = tid & 63;
  const int wave = tid >> 6;
  const int b    = blockIdx.x;
  const int u0   = b * 4;
  unsigned* flags = Sync;

  // stage H-part W (k in [0,1024)) as bf16 B-fragments
  for (int e = tid; e < 2048; e += NTHR){
    int kb = e >> 6, l = e & 63;
    int n = l & 15, kq2 = l >> 4;
    int gcol = ((n >> 2) << 10) + u0 + (n & 3);
    int k = kb*32 + kq2*8;
    Wlds[kb][l] = ld8_f32_bf16(Ww + (size_t)gcol*KTOT + k);
  }

  const int kq   = lane >> 4;
  const int m    = wave*16 + (lane & 15);
  const int ul   = lane & 3;
  const int gate = (lane >> 2) & 3;

  float C[4] = {0.f, 0.f, 0.f, 0.f};

  __syncthreads();

  // per-lane pointers (element offsets)
  const unsigned short* hp0 = Hbuf + m*HIDN + kq*8;                 // hprev when t even
  const unsigned short* hp1 = Hbuf + N_SAMP*HIDN + m*HIDN + kq*8;   // hprev when t odd
  unsigned short* hsE = Hbuf + N_SAMP*HIDN + (wave*16 + kq*4)*HIDN + u0 + ul;  // hnext, t even
  unsigned short* hsO = Hbuf + (wave*16 + kq*4)*HIDN + u0 + ul;               // hnext, t odd

  const unsigned short* gstep = G + (((size_t)b*4 + wave)*16 + (kq*4 + ul))*16;
  uint4 ga  = *reinterpret_cast<const uint4*>(gstep);
  uint4 gb2 = *reinterpret_cast<const uint4*>(gstep + 8);

  for (int t = 0; t < SEQ; ++t){
    const unsigned short* hp = (t & 1) ? hp1 : hp0;

    // ---- H loads: 64x 8B coherence-point reads (relaxed agent -> sc1, pipelined) ----
    short8 hh[32];
    #pragma unroll
    for (int kb = 0; kb < 32; ++kb){
      LL2 ll;
      ll.a = ld_agent_u64(hp + kb*32);
      ll.b = ld_agent_u64(hp + kb*32 + 4);
      hh[kb] = __builtin_bit_cast(short8, ll);
    }

    // ---- prefetch G(t+1) (read-only, regular cached loads) ----
    int tn = (t < SEQ-1) ? t+1 : t;
    const unsigned short* gp = gstep + (size_t)tn * 262144;
    uint4 na = *reinterpret_cast<const uint4*>(gp);
    uint4 nb = *reinterpret_cast<const uint4*>(gp + 8);

    // ---- MFMA chain, 4-way split accumulators, W from LDS ----
    floatx4 a0 = {0.f,0.f,0.f,0.f}, a1 = a0, a2 = a0, a3 = a0;
    #pragma unroll
    for (int kb = 0; kb < 32; kb += 4){
      a0 = __builtin_amdgcn_mfma_f32_16x16x32_bf16(hh[kb+0], Wlds[kb+0][lane], a0, 0,0,0);
      a1 = __builtin_amdgcn_mfma_f32_16x16x32_bf16(hh[kb+1], Wlds[kb+1][lane], a1, 0,0,0);
      a2 = __builtin_amdgcn_mfma_f32_16x16x32_bf16(hh[kb+2], Wlds[kb+2][lane], a2, 0,0,0);
      a3 = __builtin_amdgcn_mfma_f32_16x16x32_bf16(hh[kb+3], Wlds[kb+3][lane], a3, 0,0,0);
    }
    floatx4 acc = (a0 + a1) + (a2 + a3);

    // ---- gather i,f,o,g across lanes ----
    int base = lane & 51;
    float v0[4], v1[4], v2[4], v3[4];
    #pragma unroll
    for (int r = 0; r < 4; ++r){
      v0[r] = __shfl(acc[r], base);
      v1[r] = __shfl(acc[r], base | 4);
      v2[r] = __shfl(acc[r], base | 8);
      v3[r] = __shfl(acc[r], base | 12);
    }
    if (gate == 0){
      unsigned gw[8] = {ga.x,ga.y,ga.z,ga.w,gb2.x,gb2.y,gb2.z,gb2.w};
      unsigned short* hsb = (t & 1) ? hsO : hsE;
      #pragma unroll
      for (int r = 0; r < 4; ++r){
        float iv = sigm(v0[r] + bf2f(gw[(0 + (r>>1))] >> ((r&1)*16)));
        float fv = sigm(v1[r] + bf2f(gw[(2 + (r>>1))] >> ((r&1)*16)));
        float ov = sigm(v2[r] + bf2f(gw[(4 + (r>>1))] >> ((r&1)*16)));
        float gv = tanh_fast(v3[r] + bf2f(gw[(6 + (r>>1))] >> ((r&1)*16)));
        C[r] = fv*C[r] + iv*gv;
        float hv = ov*tanh_fast(C[r]);
        // pack two adjacent bf16 columns (ul, ul^1) into one 4B agent store
        unsigned hb = (unsigned)f2bf(hv);
        unsigned pr = (unsigned)__shfl_xor((int)hb, 1);
        if ((ul & 1) == 0)
          st_agent_u32((unsigned*)(hsb + r*HIDN), hb | (pr << 16));
        if (t == SEQ-1){
          int s = wave*16 + kq*4 + r;
          Out[s*HIDN + u0 + ul] = hv;
        }
      }
    }

    // ---- fence-free barrier ----
    if (t < SEQ-1){
      __builtin_amdgcn_s_waitcnt(0);   // own H stores acked at coherence point
      __syncthreads();                 // all waves drained
      if (wave == 0){
        if (lane == 0) st_agent_u32(&flags[b], (unsigned)(t+1));
        unsigned* fp = flags + lane*4;
        unsigned tgt = (unsigned)(t+1);
        for (;;){
          unsigned long long f0 = ld_agent_u64(fp);
          unsigned long long f1 = ld_agent_u64(fp + 2);
          bool ok = ((unsigned)f0 >= tgt) & ((unsigned)(f0>>32) >= tgt) &
                    ((unsigned)f1 >= tgt) & ((unsigned)(f1>>32) >= tgt);
          if (__all(ok)) break;
          __builtin_amdgcn_s_sleep(1);
        }
      }
      __syncthreads();
    }
    ga = na; gb2 = nb;
  }
}

// ---------------- fallback (round-2 kernel, used if ws too small) ----------------
__launch_bounds__(NTHR, 1)
__global__ void lstm_fb(const int* __restrict__ Xi, const float* __restrict__ E,
                        const float* __restrict__ Ww, const float* __restrict__ Wb,
                        float* __restrict__ Out, unsigned short* __restrict__ Hbuf,
                        unsigned* __restrict__ Cnt)
{
  __shared__ short8 Wlds[64][64];
  const int tid  = threadIdx.x;
  const int lane = tid & 63;
  const int wave = tid >> 6;
  const int u0   = blockIdx.x * 4;
  for (int e = tid; e < 4096; e += NTHR){
    int kb = e >> 6, l = e & 63;
    int n = l & 15, kq2 = l >> 4;
    int gcol = ((n >> 2) << 10) + u0 + (n & 3);
    int k = kb*32 + kq2*8;
    Wlds[kb][l] = ld8_f32_bf16(Ww + (size_t)gcol*KTOT + k);
  }
  const int kq   = lane >> 4;
  const int m    = wave*16 + (lane & 15);
  const int ul   = lane & 3;
  const int gate = (lane >> 2) & 3;
  const float bi = Wb[0*HIDN + u0 + ul];
  const float bf = Wb[1*HIDN + u0 + ul];
  const float bo = Wb[2*HIDN + u0 + ul];
  const float bg = Wb[3*HIDN + u0 + ul];
  float C[4] = {0.f, 0.f, 0.f, 0.f};
  __syncthreads();
  unsigned short* hb0 = Hbuf;
  unsigned short* hb1 = Hbuf + N_SAMP*HIDN;
  floatx4 accE = {0.f, 0.f, 0.f, 0.f};
  {
    int tok = Xi[m*SEQ + 0];
    const float* xr = E + (size_t)tok*EMBN + kq*8;
    #pragma unroll
    for (int kb = 0; kb < 32; ++kb)
      accE = __builtin_amdgcn_mfma_f32_16x16x32_bf16(ld8_f32_bf16(xr + kb*32), Wlds[32+kb][lane], accE, 0, 0, 0);
  }
  for (int t = 0; t < SEQ; ++t){
    const unsigned short* hprev = (t & 1) ? hb1 : hb0;
    unsigned short*       hnext = (t & 1) ? hb0 : hb1;
    floatx4 acc = accE;
    const short8* hp = reinterpret_cast<const short8*>(hprev + m*HIDN + kq*8);
    #pragma unroll
    for (int kb = 0; kb < 32; ++kb)
      acc = __builtin_amdgcn_mfma_f32_16x16x32_bf16(hp[kb*4], Wlds[kb][lane], acc, 0, 0, 0);
    int base = lane & 51;
    float v0[4], v1[4], v2[4], v3[4];
    #pragma unroll
    for (int r = 0; r < 4; ++r){
      v0[r] = __shfl(acc[r], base);
      v1[r] = __shfl(acc[r], base | 4);
      v2[r] = __shfl(acc[r], base | 8);
      v3[r] = __shfl(acc[r], base | 12);
    }
    if (gate == 0){
      #pragma unroll
      for (int r = 0; r < 4; ++r){
        float iv = sigm(v0[r] + bi);
        float fv = sigm(v1[r] + bf);
        float ov = sigm(v2[r] + bo);
        float gv = tanh_fast(v3[r] + bg);
        C[r] = fv*C[r] + iv*gv;
        float hv = ov*tanh_fast(C[r]);
        int s = wave*16 + kq*4 + r;
        hnext[s*HIDN + u0 + ul] = f2bf(hv);
        if (t == SEQ-1) Out[s*HIDN + u0 + ul] = hv;
      }
    }
    if (t < SEQ-1){
      __syncthreads();
      if (tid == 0){ __threadfence(); atomicAdd(Cnt, 1u); }
      floatx4 aE = {0.f, 0.f, 0.f, 0.f};
      int tok = Xi[m*SEQ + t + 1];
      const float* xr = E + (size_t)tok*EMBN + kq*8;
      #pragma unroll
      for (int kb = 0; kb < 32; ++kb)
        aE = __builtin_amdgcn_mfma_f32_16x16x32_bf16(ld8_f32_bf16(xr + kb*32), Wlds[32+kb][lane], aE, 0, 0, 0);
      accE = aE;
      if (tid == 0){
        unsigned tgt = (unsigned)NBLK * (unsigned)(t + 1);
        while (__hip_atomic_load(Cnt, __ATOMIC_RELAXED, __HIP_MEMORY_SCOPE_AGENT) < tgt)
          __builtin_amdgcn_s_sleep(2);
        __threadfence();
      }
      __syncthreads();
    }
  }
}

extern "C" void kernel_launch(void* const* d_in, const int* in_sizes, int n_in,
                              void* d_out, int out_size, void* d_ws, size_t ws_size,
                              hipStream_t stream) {
  const int*   Xi = (const int*)d_in[0];
  const float* E  = (const float*)d_in[1];
  const float* Ww = (const float*)d_in[2];
  const float* Wb = (const float*)d_in[3];
  float*       out = (float*)d_out;

  if (ws_size >= WS_NEED){
    unsigned short* hbuf = (unsigned short*)((char*)d_ws + WS_HBUF);
    unsigned*       sync = (unsigned*)((char*)d_ws + WS_SYNC);
    unsigned short* xe   = (unsigned short*)((char*)d_ws + WS_XE);
    unsigned short* wxb  = (unsigned short*)((char*)d_ws + WS_WXB);
    unsigned short* g    = (unsigned short*)((char*)d_ws + WS_G);

    hipMemsetAsync(d_ws, 0, WS_XE, stream);   // zero Hbuf + sync flags

    gather_cvt<<<18432, 256, 0, stream>>>(Xi, E, Ww, xe, wxb);
    gemm_x<<<4096, 256, 0, stream>>>(xe, wxb, Wb, g);

    void* args[] = {(void*)&Ww, (void*)&g, (void*)&out, (void*)&hbuf, (void*)&sync};
    hipLaunchCooperativeKernel((void*)lstm_main, dim3(NBLK), dim3(NTHR), args, 0, stream);
  } else {
    unsigned short* hbuf = (unsigned short*)d_ws;
    unsigned*       cnt  = (unsigned*)((char*)d_ws + 262144);
    hipMemsetAsync(d_ws, 0, 262144 + 256, stream);
    void* args[] = {(void*)&Xi, (void*)&E, (void*)&Ww, (void*)&Wb,
                    (void*)&out, (void*)&hbuf, (void*)&cnt};
    hipLaunchCooperativeKernel((void*)lstm_fb, dim3(NBLK), dim3(NTHR), args, 0, stream);
  }
}

// Round 6
// 4519.579 us; speedup vs baseline: 2.4617x; 1.5858x over previous
//
#include <hip/hip_runtime.h>
#include <hip/hip_bf16.h>

typedef __attribute__((ext_vector_type(8))) short short8;
typedef __attribute__((ext_vector_type(4))) float floatx4;

#define N_SAMP 64
#define HIDN   1024
#define EMBN   1024
#define SEQ    512
#define KTOT   2048
#define NBLK   256
#define NTHR   256

// ws layout (main path)
#define WS_HBUF   0u
#define WS_SYNC   262144u            // flags[256]
#define WS_XE     270336u            // 32768 x 1024 bf16 = 67,108,864
#define WS_WXB    67379200u          // 4096 x 1024 bf16  =  8,388,608
#define WS_G      75767808u          // 32768 x 4096 bf16 = 268,435,456
#define WS_NEED   344203264ull

__device__ __forceinline__ float sigm(float x){ return __builtin_amdgcn_rcpf(1.f + __expf(-x)); }
__device__ __forceinline__ float tanh_fast(float x){ return 2.f*__builtin_amdgcn_rcpf(1.f + __expf(-2.f*x)) - 1.f; }
__device__ __forceinline__ unsigned short f2bf(float f){
  unsigned u = __float_as_uint(f);
  return (unsigned short)((u + 0x7FFFu + ((u >> 16) & 1u)) >> 16);
}
__device__ __forceinline__ float bf2f(unsigned v){ return __uint_as_float((v & 0xffffu) << 16); }
__device__ __forceinline__ short8 ld8_f32_bf16(const float* p){
  floatx4 a = *reinterpret_cast<const floatx4*>(p);
  floatx4 b = *reinterpret_cast<const floatx4*>(p + 4);
  short8 r;
  r[0]=(short)f2bf(a[0]); r[1]=(short)f2bf(a[1]); r[2]=(short)f2bf(a[2]); r[3]=(short)f2bf(a[3]);
  r[4]=(short)f2bf(b[0]); r[5]=(short)f2bf(b[1]); r[6]=(short)f2bf(b[2]); r[7]=(short)f2bf(b[3]);
  return r;
}

struct LL2 { unsigned long long a, b; };

// relaxed agent-scope accessors -> coherence-point (sc1) ops, no fences
__device__ __forceinline__ unsigned long long ld_agent_u64(const void* p){
  return __hip_atomic_load((const unsigned long long*)p, __ATOMIC_RELAXED, __HIP_MEMORY_SCOPE_AGENT);
}
__device__ __forceinline__ void st_agent_u32(unsigned* p, unsigned v){
  __hip_atomic_store(p, v, __ATOMIC_RELAXED, __HIP_MEMORY_SCOPE_AGENT);
}
__device__ __forceinline__ void st_agent_u64(void* p, unsigned long long v){
  __hip_atomic_store((unsigned long long*)p, v, __ATOMIC_RELAXED, __HIP_MEMORY_SCOPE_AGENT);
}

// ---------------- gather/convert: Xe = bf16(E[X]), Wxb = bf16(Wx) ----------------
__global__ void gather_cvt(const int* __restrict__ Xi, const float* __restrict__ E,
                           const float* __restrict__ Ww,
                           unsigned short* __restrict__ Xe, unsigned short* __restrict__ Wxb)
{
  const int tid = threadIdx.x;
  const int inner = (tid & 127) * 8;
  if (blockIdx.x < 16384){
    int row = blockIdx.x*2 + (tid >> 7);
    int tok = Xi[row];
    short8 v = ld8_f32_bf16(E + (size_t)tok*EMBN + inner);
    *reinterpret_cast<short8*>(Xe + (size_t)row*EMBN + inner) = v;
  } else {
    int n = (blockIdx.x - 16384)*2 + (tid >> 7);
    short8 v = ld8_f32_bf16(Ww + (size_t)n*KTOT + HIDN + inner);
    *reinterpret_cast<short8*>(Wxb + (size_t)n*EMBN + inner) = v;
  }
}

// ---------------- precompute GEMM: G = Xe @ Wxb^T + bias, packed layout ----------------
__launch_bounds__(256, 2)
__global__ void gemm_x(const unsigned short* __restrict__ Xe, const unsigned short* __restrict__ Wxb,
                       const float* __restrict__ Wb, unsigned short* __restrict__ G)
{
  __shared__ unsigned short As[256][40];
  __shared__ unsigned short Bs[128][40];
  const int tid  = threadIdx.x;
  const int lane = tid & 63, wave = tid >> 6;
  const int rb = blockIdx.x >> 5, cb = blockIdx.x & 31;
  const int r0 = rb * 256, c0 = cb * 128;
  const int mloc = lane & 15, kq = lane >> 4;

  floatx4 acc[4][8];
  #pragma unroll
  for (int i=0;i<4;++i)
    #pragma unroll
    for (int j=0;j<8;++j) acc[i][j] = (floatx4){0.f,0.f,0.f,0.f};

  for (int kb = 0; kb < 32; ++kb){
    int k0 = kb * 32;
    __syncthreads();
    #pragma unroll
    for (int idx = tid; idx < 1024; idx += 256){
      int row = idx >> 2, ch = idx & 3;
      *reinterpret_cast<uint4*>(&As[row][ch*8]) =
        *reinterpret_cast<const uint4*>(&Xe[(size_t)(r0+row)*1024 + k0 + ch*8]);
    }
    #pragma unroll
    for (int idx = tid; idx < 512; idx += 256){
      int n = idx >> 2, ch = idx & 3;
      *reinterpret_cast<uint4*>(&Bs[n][ch*8]) =
        *reinterpret_cast<const uint4*>(&Wxb[(size_t)(c0+n)*1024 + k0 + ch*8]);
    }
    __syncthreads();
    short8 af[4], bfr[8];
    #pragma unroll
    for (int rt=0; rt<4; ++rt) af[rt]  = *reinterpret_cast<const short8*>(&As[wave*64 + rt*16 + mloc][kq*8]);
    #pragma unroll
    for (int ct=0; ct<8; ++ct) bfr[ct] = *reinterpret_cast<const short8*>(&Bs[ct*16 + mloc][kq*8]);
    #pragma unroll
    for (int rt=0; rt<4; ++rt)
      #pragma unroll
      for (int ct=0; ct<8; ++ct)
        acc[rt][ct] = __builtin_amdgcn_mfma_f32_16x16x32_bf16(af[rt], bfr[ct], acc[rt][ct], 0,0,0);
  }

  const int s  = r0 >> 9;
  const int wc = s >> 4, kqc = (s >> 2) & 3, rc = s & 3;
  #pragma unroll
  for (int rt=0; rt<4; ++rt){
    int rowbase = r0 + wave*64 + rt*16 + kq*4;
    #pragma unroll
    for (int ct=0; ct<8; ++ct){
      int col = c0 + ct*16 + mloc;
      float bias = Wb[col];
      int g = col >> 10, bb = (col >> 2) & 255, ul = col & 3;
      #pragma unroll
      for (int r=0; r<4; ++r){
        int t = (rowbase + r) & 511;
        size_t addr = ((((size_t)t*256 + bb)*4 + wc)*16 + (kqc*4 + ul))*16 + (g*4 + rc);
        G[addr] = f2bf(acc[rt][ct][r] + bias);
      }
    }
  }
}

// ---------------- recurrence: 256 blocks cooperative; H in A-frag consumption layout ----------------
// H layout (per buffer, 128 KB): elem offset = (w*32+kb)*512 + half*256 + lane*4
//   holds cols [kq*8 + kb*32 + half*4, +4) of row w*16 + (lane&15), lane = kq*16+(lane&15)
__launch_bounds__(NTHR, 1)
__global__ void lstm_main(const float* __restrict__ Ww, const unsigned short* __restrict__ G,
                          float* __restrict__ Out, unsigned short* __restrict__ Hbuf,
                          unsigned* __restrict__ Sync)
{
  __shared__ short8 Wlds[32][64];
  const int tid  = threadIdx.x;
  const int lane = tid & 63;
  const int wave = tid >> 6;
  const int b    = blockIdx.x;
  const int u0   = b * 4;
  unsigned* flags = Sync;

  // stage H-part W (k in [0,1024)) as bf16 B-fragments
  for (int e = tid; e < 2048; e += NTHR){
    int kb = e >> 6, l = e & 63;
    int n = l & 15, kq2 = l >> 4;
    int gcol = ((n >> 2) << 10) + u0 + (n & 3);
    int k = kb*32 + kq2*8;
    Wlds[kb][l] = ld8_f32_bf16(Ww + (size_t)gcol*KTOT + k);
  }

  const int kq   = lane >> 4;
  const int ul   = lane & 3;
  const int gate = (lane >> 2) & 3;

  float C[4] = {0.f, 0.f, 0.f, 0.f};

  __syncthreads();

  // ---- read pointers (A-frag layout, perfectly coalesced) ----
  const unsigned short* rd0 = Hbuf + wave*16384 + lane*4;            // even-t source
  const unsigned short* rd1 = rd0 + N_SAMP*HIDN;                     // odd-t source

  // ---- write base (packed 8B per (kq,r), dense 128B per (block,wave)) ----
  // elem offset = (wave*32 + (b>>3))*512 + (b&1)*256 + ((((b&7)>>1)*16) + kq*4 + r)*4
  const int wofs = (wave*32 + (b>>3))*512 + (b&1)*256 + ((((b&7)>>1)*16) + kq*4)*4;
  unsigned short* wsE = Hbuf + N_SAMP*HIDN + wofs;   // hnext when t even
  unsigned short* wsO = Hbuf + wofs;                 // hnext when t odd

  const unsigned short* gstep = G + (((size_t)b*4 + wave)*16 + (kq*4 + ul))*16;
  uint4 ga  = *reinterpret_cast<const uint4*>(gstep);
  uint4 gb2 = *reinterpret_cast<const uint4*>(gstep + 8);

  for (int t = 0; t < SEQ; ++t){
    const unsigned short* rd = (t & 1) ? rd1 : rd0;

    // ---- H loads: 64x 8B coherence-point reads, fully coalesced ----
    short8 hh[32];
    #pragma unroll
    for (int kb = 0; kb < 32; ++kb){
      LL2 ll;
      ll.a = ld_agent_u64(rd + kb*512);
      ll.b = ld_agent_u64(rd + kb*512 + 256);
      hh[kb] = __builtin_bit_cast(short8, ll);
    }

    // ---- prefetch G(t+1) (read-only, regular cached loads) ----
    int tn = (t < SEQ-1) ? t+1 : t;
    const unsigned short* gp = gstep + (size_t)tn * 262144;
    uint4 na = *reinterpret_cast<const uint4*>(gp);
    uint4 nb = *reinterpret_cast<const uint4*>(gp + 8);

    // ---- MFMA chain, 4-way split accumulators, W from LDS ----
    floatx4 a0 = {0.f,0.f,0.f,0.f}, a1 = a0, a2 = a0, a3 = a0;
    #pragma unroll
    for (int kb = 0; kb < 32; kb += 4){
      a0 = __builtin_amdgcn_mfma_f32_16x16x32_bf16(hh[kb+0], Wlds[kb+0][lane], a0, 0,0,0);
      a1 = __builtin_amdgcn_mfma_f32_16x16x32_bf16(hh[kb+1], Wlds[kb+1][lane], a1, 0,0,0);
      a2 = __builtin_amdgcn_mfma_f32_16x16x32_bf16(hh[kb+2], Wlds[kb+2][lane], a2, 0,0,0);
      a3 = __builtin_amdgcn_mfma_f32_16x16x32_bf16(hh[kb+3], Wlds[kb+3][lane], a3, 0,0,0);
    }
    floatx4 acc = (a0 + a1) + (a2 + a3);

    // ---- gather i,f,o,g across lanes ----
    int base = lane & 51;
    float v0[4], v1[4], v2[4], v3[4];
    #pragma unroll
    for (int r = 0; r < 4; ++r){
      v0[r] = __shfl(acc[r], base);
      v1[r] = __shfl(acc[r], base | 4);
      v2[r] = __shfl(acc[r], base | 8);
      v3[r] = __shfl(acc[r], base | 12);
    }
    if (gate == 0){
      unsigned gw[8] = {ga.x,ga.y,ga.z,ga.w,gb2.x,gb2.y,gb2.z,gb2.w};
      unsigned short* wsb = (t & 1) ? wsO : wsE;
      #pragma unroll
      for (int r = 0; r < 4; ++r){
        float iv = sigm(v0[r] + bf2f(gw[(0 + (r>>1))] >> ((r&1)*16)));
        float fv = sigm(v1[r] + bf2f(gw[(2 + (r>>1))] >> ((r&1)*16)));
        float ov = sigm(v2[r] + bf2f(gw[(4 + (r>>1))] >> ((r&1)*16)));
        float gv = tanh_fast(v3[r] + bf2f(gw[(6 + (r>>1))] >> ((r&1)*16)));
        C[r] = fv*C[r] + iv*gv;
        float hv = ov*tanh_fast(C[r]);
        unsigned hb = (unsigned)f2bf(hv);
        // pack the quad's 4 unit-columns into one aligned 8B word
        unsigned b0 = (unsigned)__shfl((int)hb, base);
        unsigned b1 = (unsigned)__shfl((int)hb, base | 1);
        unsigned b2 = (unsigned)__shfl((int)hb, base | 2);
        unsigned b3 = (unsigned)__shfl((int)hb, base | 3);
        if (ul == 0){
          unsigned long long pk = (unsigned long long)(b0 & 0xffffu)
                                | ((unsigned long long)(b1 & 0xffffu) << 16)
                                | ((unsigned long long)(b2 & 0xffffu) << 32)
                                | ((unsigned long long)(b3 & 0xffffu) << 48);
          st_agent_u64(wsb + r*4, pk);
        }
        if (t == SEQ-1){
          int s = wave*16 + kq*4 + r;
          Out[s*HIDN + u0 + ul] = hv;
        }
      }
    }

    // ---- fence-free barrier ----
    if (t < SEQ-1){
      __builtin_amdgcn_s_waitcnt(0);   // own H stores acked at coherence point
      __syncthreads();                 // all waves drained
      if (wave == 0){
        if (lane == 0) st_agent_u32(&flags[b], (unsigned)(t+1));
        unsigned* fp = flags + lane*4;
        unsigned tgt = (unsigned)(t+1);
        for (;;){
          unsigned long long f0 = ld_agent_u64(fp);
          unsigned long long f1 = ld_agent_u64(fp + 2);
          bool ok = ((unsigned)f0 >= tgt) & ((unsigned)(f0>>32) >= tgt) &
                    ((unsigned)f1 >= tgt) & ((unsigned)(f1>>32) >= tgt);
          if (__all(ok)) break;
          __builtin_amdgcn_s_sleep(1);
        }
      }
      __syncthreads();
    }
    ga = na; gb2 = nb;
  }
}

// ---------------- fallback (round-2 kernel, used if ws too small) ----------------
__launch_bounds__(NTHR, 1)
__global__ void lstm_fb(const int* __restrict__ Xi, const float* __restrict__ E,
                        const float* __restrict__ Ww, const float* __restrict__ Wb,
                        float* __restrict__ Out, unsigned short* __restrict__ Hbuf,
                        unsigned* __restrict__ Cnt)
{
  __shared__ short8 Wlds[64][64];
  const int tid  = threadIdx.x;
  const int lane = tid & 63;
  const int wave = tid >> 6;
  const int u0   = blockIdx.x * 4;
  for (int e = tid; e < 4096; e += NTHR){
    int kb = e >> 6, l = e & 63;
    int n = l & 15, kq2 = l >> 4;
    int gcol = ((n >> 2) << 10) + u0 + (n & 3);
    int k = kb*32 + kq2*8;
    Wlds[kb][l] = ld8_f32_bf16(Ww + (size_t)gcol*KTOT + k);
  }
  const int kq   = lane >> 4;
  const int m    = wave*16 + (lane & 15);
  const int ul   = lane & 3;
  const int gate = (lane >> 2) & 3;
  const float bi = Wb[0*HIDN + u0 + ul];
  const float bf = Wb[1*HIDN + u0 + ul];
  const float bo = Wb[2*HIDN + u0 + ul];
  const float bg = Wb[3*HIDN + u0 + ul];
  float C[4] = {0.f, 0.f, 0.f, 0.f};
  __syncthreads();
  unsigned short* hb0 = Hbuf;
  unsigned short* hb1 = Hbuf + N_SAMP*HIDN;
  floatx4 accE = {0.f, 0.f, 0.f, 0.f};
  {
    int tok = Xi[m*SEQ + 0];
    const float* xr = E + (size_t)tok*EMBN + kq*8;
    #pragma unroll
    for (int kb = 0; kb < 32; ++kb)
      accE = __builtin_amdgcn_mfma_f32_16x16x32_bf16(ld8_f32_bf16(xr + kb*32), Wlds[32+kb][lane], accE, 0, 0, 0);
  }
  for (int t = 0; t < SEQ; ++t){
    const unsigned short* hprev = (t & 1) ? hb1 : hb0;
    unsigned short*       hnext = (t & 1) ? hb0 : hb1;
    floatx4 acc = accE;
    const short8* hp = reinterpret_cast<const short8*>(hprev + m*HIDN + kq*8);
    #pragma unroll
    for (int kb = 0; kb < 32; ++kb)
      acc = __builtin_amdgcn_mfma_f32_16x16x32_bf16(hp[kb*4], Wlds[kb][lane], acc, 0, 0, 0);
    int base = lane & 51;
    float v0[4], v1[4], v2[4], v3[4];
    #pragma unroll
    for (int r = 0; r < 4; ++r){
      v0[r] = __shfl(acc[r], base);
      v1[r] = __shfl(acc[r], base | 4);
      v2[r] = __shfl(acc[r], base | 8);
      v3[r] = __shfl(acc[r], base | 12);
    }
    if (gate == 0){
      #pragma unroll
      for (int r = 0; r < 4; ++r){
        float iv = sigm(v0[r] + bi);
        float fv = sigm(v1[r] + bf);
        float ov = sigm(v2[r] + bo);
        float gv = tanh_fast(v3[r] + bg);
        C[r] = fv*C[r] + iv*gv;
        float hv = ov*tanh_fast(C[r]);
        int s = wave*16 + kq*4 + r;
        hnext[s*HIDN + u0 + ul] = f2bf(hv);
        if (t == SEQ-1) Out[s*HIDN + u0 + ul] = hv;
      }
    }
    if (t < SEQ-1){
      __syncthreads();
      if (tid == 0){ __threadfence(); atomicAdd(Cnt, 1u); }
      floatx4 aE = {0.f, 0.f, 0.f, 0.f};
      int tok = Xi[m*SEQ + t + 1];
      const float* xr = E + (size_t)tok*EMBN + kq*8;
      #pragma unroll
      for (int kb = 0; kb < 32; ++kb)
        aE = __builtin_amdgcn_mfma_f32_16x16x32_bf16(ld8_f32_bf16(xr + kb*32), Wlds[32+kb][lane], aE, 0, 0, 0);
      accE = aE;
      if (tid == 0){
        unsigned tgt = (unsigned)NBLK * (unsigned)(t + 1);
        while (__hip_atomic_load(Cnt, __ATOMIC_RELAXED, __HIP_MEMORY_SCOPE_AGENT) < tgt)
          __builtin_amdgcn_s_sleep(2);
        __threadfence();
      }
      __syncthreads();
    }
  }
}

extern "C" void kernel_launch(void* const* d_in, const int* in_sizes, int n_in,
                              void* d_out, int out_size, void* d_ws, size_t ws_size,
                              hipStream_t stream) {
  const int*   Xi = (const int*)d_in[0];
  const float* E  = (const float*)d_in[1];
  const float* Ww = (const float*)d_in[2];
  const float* Wb = (const float*)d_in[3];
  float*       out = (float*)d_out;

  if (ws_size >= WS_NEED){
    unsigned short* hbuf = (unsigned short*)((char*)d_ws + WS_HBUF);
    unsigned*       sync = (unsigned*)((char*)d_ws + WS_SYNC);
    unsigned short* xe   = (unsigned short*)((char*)d_ws + WS_XE);
    unsigned short* wxb  = (unsigned short*)((char*)d_ws + WS_WXB);
    unsigned short* g    = (unsigned short*)((char*)d_ws + WS_G);

    hipMemsetAsync(d_ws, 0, WS_XE, stream);   // zero Hbuf + sync flags

    gather_cvt<<<18432, 256, 0, stream>>>(Xi, E, Ww, xe, wxb);
    gemm_x<<<4096, 256, 0, stream>>>(xe, wxb, Wb, g);

    void* args[] = {(void*)&Ww, (void*)&g, (void*)&out, (void*)&hbuf, (void*)&sync};
    hipLaunchCooperativeKernel((void*)lstm_main, dim3(NBLK), dim3(NTHR), args, 0, stream);
  } else {
    unsigned short* hbuf = (unsigned short*)d_ws;
    unsigned*       cnt  = (unsigned*)((char*)d_ws + 262144);
    hipMemsetAsync(d_ws, 0, 262144 + 256, stream);
    void* args[] = {(void*)&Xi, (void*)&E, (void*)&Ww, (void*)&Wb,
                    (void*)&out, (void*)&hbuf, (void*)&cnt};
    hipLaunchCooperativeKernel((void*)lstm_fb, dim3(NBLK), dim3(NTHR), args, 0, stream);
  }
}